// Round 2
// baseline (2077.386 us; speedup 1.0000x reference)
//
#include <hip/hip_runtime.h>
#include <math.h>
#include <float.h>

// Problem constants
#define N_SEQ 2048
#define DIMN  1024
#define NH    16
#define DH    64
#define ROT   32
#define MEM   16
#define JTOT  (N_SEQ + MEM)   // 2064
#define JP    2112            // padded to x32 (pad keys zeroed, masked)
#define NB    32
#define REL_SCALE 8.0f
#define JSP   512             // j-split quantum; c<3: [512c,512c+512), c=3: [1536,2112)
#define JPLANE 257            // LDS plane stride (odd -> bank spread)

typedef __attribute__((ext_vector_type(8))) _Float16 half8;
typedef __attribute__((ext_vector_type(4))) float floatx4;

// ---------------------------------------------------------------------------
// Generic fp32 GEMM: C = A(MxK) @ B(KxN) (+bias). 64x64 tile, BK=16, 4x4/thread.
// ---------------------------------------------------------------------------
__global__ __launch_bounds__(256) void gemm_f32(
    const float* __restrict__ A, const float* __restrict__ B,
    float* __restrict__ C, const float* __restrict__ bias,
    int M, int K, int N)
{
  __shared__ float As[16][68];
  __shared__ float Bs[16][64];
  const int tid = threadIdx.x;
  const int tx = tid & 15, ty = tid >> 4;
  const int m0 = blockIdx.y * 64, n0 = blockIdx.x * 64;
  const int la_r = tid >> 2;
  const int la_k = (tid & 3) * 4;
  const int lb_k = tid >> 4;
  const int lb_n = (tid & 15) * 4;
  float acc[4][4] = {};
  for (int k0 = 0; k0 < K; k0 += 16) {
    float4 av = *(const float4*)&A[(size_t)(m0 + la_r) * K + k0 + la_k];
    float4 bv = *(const float4*)&B[(size_t)(k0 + lb_k) * N + n0 + lb_n];
    __syncthreads();
    As[la_k + 0][la_r] = av.x;
    As[la_k + 1][la_r] = av.y;
    As[la_k + 2][la_r] = av.z;
    As[la_k + 3][la_r] = av.w;
    *(float4*)&Bs[lb_k][lb_n] = bv;
    __syncthreads();
#pragma unroll
    for (int kk = 0; kk < 16; ++kk) {
      float4 a = *(const float4*)&As[kk][ty * 4];
      float4 b = *(const float4*)&Bs[kk][tx * 4];
      acc[0][0] += a.x * b.x; acc[0][1] += a.x * b.y; acc[0][2] += a.x * b.z; acc[0][3] += a.x * b.w;
      acc[1][0] += a.y * b.x; acc[1][1] += a.y * b.y; acc[1][2] += a.y * b.z; acc[1][3] += a.y * b.w;
      acc[2][0] += a.z * b.x; acc[2][1] += a.z * b.y; acc[2][2] += a.z * b.z; acc[2][3] += a.z * b.w;
      acc[3][0] += a.w * b.x; acc[3][1] += a.w * b.y; acc[3][2] += a.w * b.z; acc[3][3] += a.w * b.w;
    }
  }
  float4 bb = make_float4(0.f, 0.f, 0.f, 0.f);
  if (bias) bb = *(const float4*)&bias[n0 + tx * 4];
#pragma unroll
  for (int r = 0; r < 4; ++r) {
    float4 o = make_float4(acc[r][0] + bb.x, acc[r][1] + bb.y,
                           acc[r][2] + bb.z, acc[r][3] + bb.w);
    *(float4*)&C[(size_t)(m0 + ty * 4 + r) * N + n0 + tx * 4] = o;
  }
}

// ---------------------------------------------------------------------------
// Rotary + l2norm + fp16 layout. qh scaled by 1/clip(exp(qk_scale),0.01).
// kh/vh padded rows [JTOT,JP) zeroed.
// ---------------------------------------------------------------------------
__global__ __launch_bounds__(256) void postproc(
    const float* __restrict__ tmp, const float* __restrict__ rot,
    const float* __restrict__ mem_k, const float* __restrict__ mem_v,
    const float* __restrict__ qk_scale,
    _Float16* __restrict__ qh, _Float16* __restrict__ kh, _Float16* __restrict__ vh)
{
  const int gw = (blockIdx.x * 256 + threadIdx.x) >> 6;
  const int lane = threadIdx.x & 63;
  const int TQ = NH * N_SEQ;
  const int TM = TQ + NH * MEM;
  const int TP = TM + NH * (JP - JTOT);
  if (gw < TQ) {
    const int h = gw >> 11;
    const int i = gw & (N_SEQ - 1);
    const size_t base = (size_t)i * DIMN + h * DH + lane;
    float q = tmp[base];
    float k = tmp[base + (size_t)N_SEQ * DIMN];
    float v = tmp[base + 2 * (size_t)N_SEQ * DIMN];
    float cf = 1.f, sf = 0.f;
    if (lane < ROT) { float f = rot[(size_t)i * ROT + lane]; cf = cosf(f); sf = sinf(f); }
    float qp = __shfl_xor(q, 16);
    float kp = __shfl_xor(k, 16);
    float vp = __shfl_xor(v, 16);
    if (lane < ROT) {
      float sgn = (lane < 16) ? -1.f : 1.f;
      q = q * cf + sgn * qp * sf;
      k = k * cf + sgn * kp * sf;
      v = v * cf + sgn * vp * sf;
    }
    float nq = q * q, nk = k * k;
#pragma unroll
    for (int off = 32; off; off >>= 1) { nq += __shfl_xor(nq, off); nk += __shfl_xor(nk, off); }
    q *= 1.f / fmaxf(sqrtf(nq), 1e-12f);
    k *= 1.f / fmaxf(sqrtf(nk), 1e-12f);
    float scl = 1.0f / fmaxf(__expf(qk_scale[h]), 0.01f);
    qh[((size_t)h * N_SEQ + i) * DH + lane] = (_Float16)(q * scl);
    kh[((size_t)h * JP + MEM + i) * DH + lane] = (_Float16)k;
    vh[((size_t)h * JP + MEM + i) * DH + lane] = (_Float16)v;
  } else if (gw < TM) {
    const int r = gw - TQ;
    const int h = r >> 4, mm = r & 15;
    float k = mem_k[((size_t)h * MEM + mm) * DH + lane];
    float v = mem_v[((size_t)h * MEM + mm) * DH + lane];
    float nk = k * k;
#pragma unroll
    for (int off = 32; off; off >>= 1) nk += __shfl_xor(nk, off);
    k *= 1.f / fmaxf(sqrtf(nk), 1e-12f);
    kh[((size_t)h * JP + mm) * DH + lane] = (_Float16)k;
    vh[((size_t)h * JP + mm) * DH + lane] = (_Float16)v;
  } else if (gw < TP) {
    const int r = gw - TM;
    const int h = r / (JP - JTOT), jr = JTOT + r % (JP - JTOT);
    kh[((size_t)h * JP + jr) * DH + lane] = (_Float16)0.f;
    vh[((size_t)h * JP + jr) * DH + lane] = (_Float16)0.f;
  }
}

// ---------------------------------------------------------------------------
// vh[h][j][d] -> vT[h][d][j]  (64x64 LDS tiles)
// ---------------------------------------------------------------------------
__global__ __launch_bounds__(256) void transpose_v(
    const _Float16* __restrict__ vh, _Float16* __restrict__ vT)
{
  __shared__ _Float16 tile[64][72];
  const int h = blockIdx.y;
  const int j0 = blockIdx.x * 64;
  const int t = threadIdx.x;
#pragma unroll
  for (int p = 0; p < 2; ++p) {
    const int jr = (t >> 3) + 32 * p;
    const int dc = (t & 7) * 8;
    half8 v = *(const half8*)(vh + ((size_t)h * JP + j0 + jr) * DH + dc);
    *(half8*)&tile[jr][dc] = v;
  }
  __syncthreads();
#pragma unroll
  for (int p = 0; p < 2; ++p) {
    const int d = (t >> 3) + 32 * p;
    const int jc = (t & 7) * 8;
    half8 o;
#pragma unroll
    for (int r = 0; r < 8; ++r) o[r] = tile[jc + r][d];
    *(half8*)(vT + ((size_t)h * DH + d) * JP + j0 + jc) = o;
  }
}

__device__ __forceinline__ int rel_bucket(int n) {
  if (n < 0) n = 0;
  if (n < 16) return n;
  int v = 16 + (int)(logf((float)n * 0.0625f) * 7.6944042f);
  return v > 31 ? 31 : v;
}

// ---------------------------------------------------------------------------
// Pass 1: MFMA QK^T -> fp32 pre-mix -> running (m,l) per (k,i) per split.
// Block: 16 q-rows x 16 heads, 4 waves (4 heads each).
// ---------------------------------------------------------------------------
__global__ __launch_bounds__(256, 2) void attn_pass1(
    const _Float16* __restrict__ qh, const _Float16* __restrict__ kh,
    const float* __restrict__ pre_proj, const float* __restrict__ rel_table,
    float* __restrict__ mpart, float* __restrict__ lpart)
{
  const int i0 = blockIdx.x * 16;
  const int c = blockIdx.y;
  const int jlo = c * JSP;
  if (jlo >= i0 + 32) return;
  const int jhi = min((c < 3) ? jlo + JSP : JP, (i0 + 63) & ~31);
  const int tid = threadIdx.x;
  const int lane = tid & 63, w = tid >> 6;

  __shared__ float S_lds[32 * JPLANE];
  __shared__ float pre_s[256];
  __shared__ float relt[NB * NH];

  pre_s[tid] = pre_proj[tid];
  relt[tid] = rel_table[tid];
  relt[256 + tid] = rel_table[256 + tid];

  half8 qf[4][2];
#pragma unroll
  for (int n = 0; n < 4; ++n) {
    const int h = w * 4 + n;
    const _Float16* qb = qh + ((size_t)h * N_SEQ + i0 + (lane & 15)) * DH + (lane >> 4) * 8;
    qf[n][0] = *(const half8*)qb;
    qf[n][1] = *(const half8*)(qb + 32);
  }
  float m[16], l[16];
#pragma unroll
  for (int k = 0; k < 16; ++k) { m[k] = -1e30f; l[k] = 0.f; }
  const int mi = tid & 15;
  const int mj = tid >> 4;
  const int ig = i0 + mi;
  __syncthreads();

  for (int jb = jlo; jb < jhi; jb += 32) {
#pragma unroll
    for (int n = 0; n < 4; ++n) {
      const int h = w * 4 + n;
#pragma unroll
      for (int T = 0; T < 2; ++T) {
        floatx4 acc = {0.f, 0.f, 0.f, 0.f};
        const _Float16* kb = kh + ((size_t)h * JP + jb + 16 * T + (lane & 15)) * DH + (lane >> 4) * 8;
        acc = __builtin_amdgcn_mfma_f32_16x16x32_f16(qf[n][0], *(const half8*)kb, acc, 0, 0, 0);
        acc = __builtin_amdgcn_mfma_f32_16x16x32_f16(qf[n][1], *(const half8*)(kb + 32), acc, 0, 0, 0);
        const int jcol = (lane & 15) + 16 * T;
        const int row0 = (lane >> 4) * 4;
#pragma unroll
        for (int r = 0; r < 4; ++r) S_lds[jcol * JPLANE + h * 16 + row0 + r] = acc[r];
      }
    }
    __syncthreads();
    // mixing for (mi, jb+mj) and (mi, jb+mj+16)
    float2 sa[16];
#pragma unroll
    for (int k = 0; k < 16; ++k) { sa[k].x = 0.f; sa[k].y = 0.f; }
#pragma unroll
    for (int h = 0; h < 16; ++h) {
      float s0 = S_lds[mj * JPLANE + h * 16 + mi];
      float s1 = S_lds[(mj + 16) * JPLANE + h * 16 + mi];
#pragma unroll
      for (int kq = 0; kq < 4; ++kq) {
        float4 pv = *(const float4*)&pre_s[h * 16 + kq * 4];
        sa[kq * 4 + 0].x += s0 * pv.x; sa[kq * 4 + 0].y += s1 * pv.x;
        sa[kq * 4 + 1].x += s0 * pv.y; sa[kq * 4 + 1].y += s1 * pv.y;
        sa[kq * 4 + 2].x += s0 * pv.z; sa[kq * 4 + 2].y += s1 * pv.z;
        sa[kq * 4 + 3].x += s0 * pv.w; sa[kq * 4 + 3].y += s1 * pv.w;
      }
    }
    const int jg0 = jb + mj, jg1 = jg0 + 16;
    const bool v0 = (jg0 <= ig + MEM) && (jg0 < JTOT);
    const bool v1 = (jg1 <= ig + MEM) && (jg1 < JTOT);
    const int rb0 = rel_bucket(ig - jg0) * 16;
    const int rb1 = rel_bucket(ig - jg1) * 16;
#pragma unroll
    for (int k = 0; k < 16; ++k) {
      float s0 = v0 ? sa[k].x + relt[rb0 + k] * REL_SCALE : -1e30f;
      float s1 = v1 ? sa[k].y + relt[rb1 + k] * REL_SCALE : -1e30f;
      float mn = fmaxf(m[k], fmaxf(s0, s1));
      float e0 = v0 ? __expf(s0 - mn) : 0.f;
      float e1 = v1 ? __expf(s1 - mn) : 0.f;
      l[k] = l[k] * __expf(m[k] - mn) + e0 + e1;
      m[k] = mn;
    }
    __syncthreads();
  }
  // merge over mj threads: planes [0..15]=m, [16..31]=l at offset k*16+mi
#pragma unroll
  for (int k = 0; k < 16; ++k) {
    S_lds[mj * JPLANE + k * 16 + mi] = m[k];
    S_lds[(16 + mj) * JPLANE + k * 16 + mi] = l[k];
  }
  __syncthreads();
  const int k = tid >> 4, i2 = tid & 15;
  float M = -1e30f;
#pragma unroll
  for (int jj = 0; jj < 16; ++jj) M = fmaxf(M, S_lds[jj * JPLANE + k * 16 + i2]);
  float L = 0.f;
#pragma unroll
  for (int jj = 0; jj < 16; ++jj)
    L += S_lds[(16 + jj) * JPLANE + k * 16 + i2] * __expf(S_lds[jj * JPLANE + k * 16 + i2] - M);
  mpart[((size_t)c * NH + k) * N_SEQ + i0 + i2] = M;
  lpart[((size_t)c * NH + k) * N_SEQ + i0 + i2] = L;
}

// ---------------------------------------------------------------------------
__global__ __launch_bounds__(256) void merge_ml(
    const float* __restrict__ mpart, const float* __restrict__ lpart,
    float* __restrict__ Mf, float* __restrict__ Lf)
{
  const int t = blockIdx.x * 256 + threadIdx.x;
  const int i = t & (N_SEQ - 1);
  const int lim = (i & ~15) + 32;
  const int h = t >> 11;
  float m = -1e30f;
#pragma unroll
  for (int c = 0; c < 4; ++c)
    if (c * JSP < lim) m = fmaxf(m, mpart[((size_t)c * NH + h) * N_SEQ + i]);
  float l = 0.f;
#pragma unroll
  for (int c = 0; c < 4; ++c)
    if (c * JSP < lim) {
      float mc = mpart[((size_t)c * NH + h) * N_SEQ + i];
      l += lpart[((size_t)c * NH + h) * N_SEQ + i] * __expf(mc - m);
    }
  Mf[t] = m;
  Lf[t] = l;
}

// ---------------------------------------------------------------------------
// Pass 2: MFMA QK^T -> pre-mix -> P=exp(s-M)/L -> post-mix -> MFMA PV.
// ---------------------------------------------------------------------------
__global__ __launch_bounds__(256, 2) void attn_pass2(
    const _Float16* __restrict__ qh, const _Float16* __restrict__ kh,
    const _Float16* __restrict__ vT,
    const float* __restrict__ pre_proj, const float* __restrict__ post_proj,
    const float* __restrict__ rel_table,
    const float* __restrict__ Mf, const float* __restrict__ Lf,
    float* __restrict__ opart)
{
  const int i0 = blockIdx.x * 16;
  const int c = blockIdx.y;
  const int jlo = c * JSP;
  if (jlo >= i0 + 32) return;
  const int jhi = min((c < 3) ? jlo + JSP : JP, (i0 + 63) & ~31);
  const int tid = threadIdx.x;
  const int lane = tid & 63, w = tid >> 6;

  __shared__ float S_lds[32 * JPLANE];
  __shared__ _Float16 P_lds[16 * 16 * 40];
  __shared__ float pre_s[256];
  __shared__ float post_s[256];
  __shared__ float relt[NB * NH];

  pre_s[tid] = pre_proj[tid];
  post_s[tid] = post_proj[tid];
  relt[tid] = rel_table[tid];
  relt[256 + tid] = rel_table[256 + tid];

  half8 qf[4][2];
#pragma unroll
  for (int n = 0; n < 4; ++n) {
    const int h = w * 4 + n;
    const _Float16* qb = qh + ((size_t)h * N_SEQ + i0 + (lane & 15)) * DH + (lane >> 4) * 8;
    qf[n][0] = *(const half8*)qb;
    qf[n][1] = *(const half8*)(qb + 32);
  }
  const int mi = tid & 15;
  const int mj = tid >> 4;
  const int ig = i0 + mi;
  float Mreg[16], iL[16];
#pragma unroll
  for (int k = 0; k < 16; ++k) {
    Mreg[k] = Mf[(size_t)k * N_SEQ + ig];
    iL[k] = 1.0f / Lf[(size_t)k * N_SEQ + ig];
  }
  floatx4 oacc[4][4];
#pragma unroll
  for (int n = 0; n < 4; ++n)
#pragma unroll
    for (int T = 0; T < 4; ++T) oacc[n][T] = (floatx4){0.f, 0.f, 0.f, 0.f};
  __syncthreads();

  for (int jb = jlo; jb < jhi; jb += 32) {
#pragma unroll
    for (int n = 0; n < 4; ++n) {
      const int h = w * 4 + n;
#pragma unroll
      for (int T = 0; T < 2; ++T) {
        floatx4 acc = {0.f, 0.f, 0.f, 0.f};
        const _Float16* kb = kh + ((size_t)h * JP + jb + 16 * T + (lane & 15)) * DH + (lane >> 4) * 8;
        acc = __builtin_amdgcn_mfma_f32_16x16x32_f16(qf[n][0], *(const half8*)kb, acc, 0, 0, 0);
        acc = __builtin_amdgcn_mfma_f32_16x16x32_f16(qf[n][1], *(const half8*)(kb + 32), acc, 0, 0, 0);
        const int jcol = (lane & 15) + 16 * T;
        const int row0 = (lane >> 4) * 4;
#pragma unroll
        for (int r = 0; r < 4; ++r) S_lds[jcol * JPLANE + h * 16 + row0 + r] = acc[r];
      }
    }
    __syncthreads();
    // pre-mix
    float2 sa[16];
#pragma unroll
    for (int k = 0; k < 16; ++k) { sa[k].x = 0.f; sa[k].y = 0.f; }
#pragma unroll
    for (int h = 0; h < 16; ++h) {
      float s0 = S_lds[mj * JPLANE + h * 16 + mi];
      float s1 = S_lds[(mj + 16) * JPLANE + h * 16 + mi];
#pragma unroll
      for (int kq = 0; kq < 4; ++kq) {
        float4 pv = *(const float4*)&pre_s[h * 16 + kq * 4];
        sa[kq * 4 + 0].x += s0 * pv.x; sa[kq * 4 + 0].y += s1 * pv.x;
        sa[kq * 4 + 1].x += s0 * pv.y; sa[kq * 4 + 1].y += s1 * pv.y;
        sa[kq * 4 + 2].x += s0 * pv.z; sa[kq * 4 + 2].y += s1 * pv.z;
        sa[kq * 4 + 3].x += s0 * pv.w; sa[kq * 4 + 3].y += s1 * pv.w;
      }
    }
    const int jg0 = jb + mj, jg1 = jg0 + 16;
    const bool v0 = (jg0 <= ig + MEM) && (jg0 < JTOT);
    const bool v1 = (jg1 <= ig + MEM) && (jg1 < JTOT);
    const int rb0 = rel_bucket(ig - jg0) * 16;
    const int rb1 = rel_bucket(ig - jg1) * 16;
    float2 p[16];
#pragma unroll
    for (int k = 0; k < 16; ++k) {
      float s0 = sa[k].x + relt[rb0 + k] * REL_SCALE;
      float s1 = sa[k].y + relt[rb1 + k] * REL_SCALE;
      p[k].x = v0 ? __expf(s0 - Mreg[k]) * iL[k] : 0.f;
      p[k].y = v1 ? __expf(s1 - Mreg[k]) * iL[k] : 0.f;
    }
    // post-mix
    float2 o2[16];
#pragma unroll
    for (int k = 0; k < 16; ++k) { o2[k].x = 0.f; o2[k].y = 0.f; }
#pragma unroll
    for (int k = 0; k < 16; ++k) {
      float2 pk = p[k];
#pragma unroll
      for (int kq = 0; kq < 4; ++kq) {
        float4 po = *(const float4*)&post_s[k * 16 + kq * 4];
        o2[kq * 4 + 0].x += pk.x * po.x; o2[kq * 4 + 0].y += pk.y * po.x;
        o2[kq * 4 + 1].x += pk.x * po.y; o2[kq * 4 + 1].y += pk.y * po.y;
        o2[kq * 4 + 2].x += pk.x * po.z; o2[kq * 4 + 2].y += pk.y * po.z;
        o2[kq * 4 + 3].x += pk.x * po.w; o2[kq * 4 + 3].y += pk.y * po.w;
      }
    }
#pragma unroll
    for (int k2 = 0; k2 < 16; ++k2) {
      P_lds[(k2 * 16 + mi) * 40 + mj] = (_Float16)o2[k2].x;
      P_lds[(k2 * 16 + mi) * 40 + mj + 16] = (_Float16)o2[k2].y;
    }
    __syncthreads();
    // PV
#pragma unroll
    for (int n = 0; n < 4; ++n) {
      const int h = w * 4 + n;
      half8 af = *(const half8*)&P_lds[((h * 16) + (lane & 15)) * 40 + (lane >> 4) * 8];
#pragma unroll
      for (int T = 0; T < 4; ++T) {
        const _Float16* vb = vT + ((size_t)h * DH + 16 * T + (lane & 15)) * JP + jb + (lane >> 4) * 8;
        oacc[n][T] = __builtin_amdgcn_mfma_f32_16x16x32_f16(af, *(const half8*)vb, oacc[n][T], 0, 0, 0);
      }
    }
    __syncthreads();
  }
#pragma unroll
  for (int n = 0; n < 4; ++n) {
    const int h = w * 4 + n;
#pragma unroll
    for (int T = 0; T < 4; ++T)
#pragma unroll
      for (int r = 0; r < 4; ++r) {
        const int row = (lane >> 4) * 4 + r;
        const int col = 16 * T + (lane & 15);
        opart[((size_t)c * N_SEQ + i0 + row) * DIMN + h * DH + col] = oacc[n][T][r];
      }
  }
}

// ---------------------------------------------------------------------------
__global__ __launch_bounds__(256) void merge_ctx(
    const float* __restrict__ opart, float* __restrict__ ctx)
{
  const int t = blockIdx.x * 256 + threadIdx.x;
  const int i = t >> 8;
  const int c4 = t & 255;
  const int lim = (i & ~15) + 32;
  float4 acc = make_float4(0.f, 0.f, 0.f, 0.f);
#pragma unroll
  for (int c = 0; c < 4; ++c) {
    if (c * JSP < lim) {
      float4 v = ((const float4*)opart)[((size_t)c * N_SEQ + i) * 256 + c4];
      acc.x += v.x; acc.y += v.y; acc.z += v.z; acc.w += v.w;
    }
  }
  ((float4*)ctx)[(size_t)i * 256 + c4] = acc;
}

// ---------------------------------------------------------------------------
extern "C" void kernel_launch(void* const* d_in, const int* in_sizes, int n_in,
                              void* d_out, int out_size, void* d_ws, size_t ws_size,
                              hipStream_t stream)
{
  const float* x         = (const float*)d_in[0];
  const float* rot       = (const float*)d_in[1];
  const float* Wq        = (const float*)d_in[2];
  const float* Wk        = (const float*)d_in[3];
  const float* Wv        = (const float*)d_in[4];
  const float* Wo        = (const float*)d_in[5];
  const float* bo        = (const float*)d_in[6];
  const float* mem_k     = (const float*)d_in[7];
  const float* mem_v     = (const float*)d_in[8];
  const float* pre_proj  = (const float*)d_in[9];
  const float* post_proj = (const float*)d_in[10];
  const float* qk_scale  = (const float*)d_in[11];
  const float* rel_table = (const float*)d_in[12];
  float* out = (float*)d_out;
  float* ws  = (float*)d_ws;

  // workspace (floats): region reused: tmp (early) aliases opart/ctx (late)
  float* region = ws;                          // max(3*N*DIM, 4*N*DIM + N*DIM) = 10,485,760 f
  float* tmp    = region;
  float* opart  = region;
  float* ctx    = region + (size_t)4 * N_SEQ * DIMN;
  float* mpart  = region + 10485760;           // 4*16*2048
  float* lpart  = mpart + 131072;
  float* Mf     = lpart + 131072;
  float* Lf     = Mf + 32768;
  _Float16* qh  = (_Float16*)(Lf + 32768);     // 16*2048*64
  _Float16* kh  = qh + (size_t)NH * N_SEQ * DH;
  _Float16* vh  = kh + (size_t)NH * JP * DH;
  _Float16* vT  = vh + (size_t)NH * JP * DH;
  (void)in_sizes; (void)n_in; (void)out_size; (void)ws_size;

  dim3 gB(DIMN / 64, N_SEQ / 64);
  gemm_f32<<<gB, 256, 0, stream>>>(x, Wq, tmp, nullptr, N_SEQ, DIMN, DIMN);
  gemm_f32<<<gB, 256, 0, stream>>>(x, Wk, tmp + (size_t)N_SEQ * DIMN, nullptr, N_SEQ, DIMN, DIMN);
  gemm_f32<<<gB, 256, 0, stream>>>(x, Wv, tmp + 2 * (size_t)N_SEQ * DIMN, nullptr, N_SEQ, DIMN, DIMN);

  {
    const int waves = NH * N_SEQ + NH * MEM + NH * (JP - JTOT);
    postproc<<<waves / 4, 256, 0, stream>>>(tmp, rot, mem_k, mem_v, qk_scale, qh, kh, vh);
  }
  transpose_v<<<dim3(JP / 64, NH), 256, 0, stream>>>(vh, vT);

  attn_pass1<<<dim3(N_SEQ / 16, 4), 256, 0, stream>>>(
      qh, kh, pre_proj, rel_table, mpart, lpart);
  merge_ml<<<NH * N_SEQ / 256, 256, 0, stream>>>(mpart, lpart, Mf, Lf);
  attn_pass2<<<dim3(N_SEQ / 16, 4), 256, 0, stream>>>(
      qh, kh, vT, pre_proj, post_proj, rel_table, Mf, Lf, opart);
  merge_ctx<<<(N_SEQ * DIMN / 4) / 256, 256, 0, stream>>>(opart, ctx);

  gemm_f32<<<gB, 256, 0, stream>>>(ctx, Wo, out, bo, N_SEQ, DIMN, DIMN);
}

// Round 3
// 1546.954 us; speedup vs baseline: 1.3429x; 1.3429x over previous
//
#include <hip/hip_runtime.h>
#include <math.h>
#include <float.h>

// Problem constants
#define N_SEQ 2048
#define DIMN  1024
#define NH    16
#define DH    64
#define ROT   32
#define MEM   16
#define JTOT  (N_SEQ + MEM)   // 2064
#define JP    2112            // padded to x32 (pad keys zeroed, masked)
#define NB    32
#define REL_SCALE 8.0f
#define JSP   512             // j-split quantum
#define JPLANE 257            // LDS plane stride

typedef __attribute__((ext_vector_type(8))) _Float16 half8;
typedef __attribute__((ext_vector_type(4))) _Float16 half4;
typedef __attribute__((ext_vector_type(4))) float floatx4;

// ---------------------------------------------------------------------------
// f32 -> f16 elementwise (vectorized)
// ---------------------------------------------------------------------------
__global__ __launch_bounds__(256) void convert_f16(
    const float* __restrict__ in, _Float16* __restrict__ out, int n4)
{
  const int t = blockIdx.x * 256 + threadIdx.x;
  if (t >= n4) return;
  float4 v = ((const float4*)in)[t];
  half4 o = { (_Float16)v.x, (_Float16)v.y, (_Float16)v.z, (_Float16)v.w };
  *(half4*)&out[(size_t)t * 4] = o;
}

// ---------------------------------------------------------------------------
// W [K][N] f32 -> WT [N][K] f16 (64x64 LDS tiles)
// ---------------------------------------------------------------------------
__global__ __launch_bounds__(256) void convtrans(
    const float* __restrict__ W, _Float16* __restrict__ WT, int K, int N)
{
  __shared__ _Float16 tile[64][72];
  const int k0 = blockIdx.y * 64, n0 = blockIdx.x * 64;
  const int t = threadIdx.x;
#pragma unroll
  for (int p = 0; p < 4; ++p) {
    const int r = (t >> 4) + 16 * p;
    const int c = (t & 15) * 4;
    float4 wv = *(const float4*)&W[(size_t)(k0 + r) * N + n0 + c];
    tile[r][c + 0] = (_Float16)wv.x;
    tile[r][c + 1] = (_Float16)wv.y;
    tile[r][c + 2] = (_Float16)wv.z;
    tile[r][c + 3] = (_Float16)wv.w;
  }
  __syncthreads();
#pragma unroll
  for (int p = 0; p < 2; ++p) {
    const int n = (t >> 3) + 32 * p;
    const int kc = (t & 7) * 8;
    half8 o;
#pragma unroll
    for (int j = 0; j < 8; ++j) o[j] = tile[kc + j][n];
    *(half8*)&WT[(size_t)(n0 + n) * K + k0 + kc] = o;
  }
}

// ---------------------------------------------------------------------------
// fp16 MFMA GEMM: C(f32) = A(f16,[M][K]) @ BT(f16,[N][K])^T (+bias)
// 64x64 tile, 4 waves (16 rows each), direct global fragments.
// ---------------------------------------------------------------------------
__global__ __launch_bounds__(256) void gemm_f16(
    const _Float16* __restrict__ A, const _Float16* __restrict__ BT,
    float* __restrict__ C, const float* __restrict__ bias,
    int M, int K, int N)
{
  const int tid = threadIdx.x;
  const int w = tid >> 6, lane = tid & 63;
  const int m0 = blockIdx.y * 64 + w * 16;
  const int n0 = blockIdx.x * 64;
  const int lr = lane & 15, lk = (lane >> 4) * 8;
  const _Float16* Ap = A + (size_t)(m0 + lr) * K + lk;
  const _Float16* Bp = BT + (size_t)(n0 + lr) * K + lk;
  floatx4 acc[4];
#pragma unroll
  for (int T = 0; T < 4; ++T) acc[T] = (floatx4){0.f, 0.f, 0.f, 0.f};
#pragma unroll 2
  for (int k0 = 0; k0 < K; k0 += 32) {
    half8 af = *(const half8*)(Ap + k0);
#pragma unroll
    for (int T = 0; T < 4; ++T) {
      half8 bf = *(const half8*)(Bp + (size_t)T * 16 * K + k0);
      acc[T] = __builtin_amdgcn_mfma_f32_16x16x32_f16(af, bf, acc[T], 0, 0, 0);
    }
  }
#pragma unroll
  for (int T = 0; T < 4; ++T) {
    const int col = n0 + T * 16 + lr;
    const float bb = bias ? bias[col] : 0.f;
#pragma unroll
    for (int r = 0; r < 4; ++r) {
      const int row = m0 + (lane >> 4) * 4 + r;
      C[(size_t)row * N + col] = acc[T][r] + bb;
    }
  }
}

// ---------------------------------------------------------------------------
// Rotary + l2norm + fp16 layout. qh scaled by 1/clip(exp(qk_scale),0.01).
// ---------------------------------------------------------------------------
__global__ __launch_bounds__(256) void postproc(
    const float* __restrict__ tmp, const float* __restrict__ rot,
    const float* __restrict__ mem_k, const float* __restrict__ mem_v,
    const float* __restrict__ qk_scale,
    _Float16* __restrict__ qh, _Float16* __restrict__ kh, _Float16* __restrict__ vh)
{
  const int gw = (blockIdx.x * 256 + threadIdx.x) >> 6;
  const int lane = threadIdx.x & 63;
  const int TQ = NH * N_SEQ;
  const int TM = TQ + NH * MEM;
  const int TP = TM + NH * (JP - JTOT);
  if (gw < TQ) {
    const int h = gw >> 11;
    const int i = gw & (N_SEQ - 1);
    const size_t base = (size_t)i * DIMN + h * DH + lane;
    float q = tmp[base];
    float k = tmp[base + (size_t)N_SEQ * DIMN];
    float v = tmp[base + 2 * (size_t)N_SEQ * DIMN];
    float cf = 1.f, sf = 0.f;
    if (lane < ROT) { float f = rot[(size_t)i * ROT + lane]; cf = cosf(f); sf = sinf(f); }
    float qp = __shfl_xor(q, 16);
    float kp = __shfl_xor(k, 16);
    float vp = __shfl_xor(v, 16);
    if (lane < ROT) {
      float sgn = (lane < 16) ? -1.f : 1.f;
      q = q * cf + sgn * qp * sf;
      k = k * cf + sgn * kp * sf;
      v = v * cf + sgn * vp * sf;
    }
    float nq = q * q, nk = k * k;
#pragma unroll
    for (int off = 32; off; off >>= 1) { nq += __shfl_xor(nq, off); nk += __shfl_xor(nk, off); }
    q *= 1.f / fmaxf(sqrtf(nq), 1e-12f);
    k *= 1.f / fmaxf(sqrtf(nk), 1e-12f);
    float scl = 1.0f / fmaxf(__expf(qk_scale[h]), 0.01f);
    qh[((size_t)h * N_SEQ + i) * DH + lane] = (_Float16)(q * scl);
    kh[((size_t)h * JP + MEM + i) * DH + lane] = (_Float16)k;
    vh[((size_t)h * JP + MEM + i) * DH + lane] = (_Float16)v;
  } else if (gw < TM) {
    const int r = gw - TQ;
    const int h = r >> 4, mm = r & 15;
    float k = mem_k[((size_t)h * MEM + mm) * DH + lane];
    float v = mem_v[((size_t)h * MEM + mm) * DH + lane];
    float nk = k * k;
#pragma unroll
    for (int off = 32; off; off >>= 1) nk += __shfl_xor(nk, off);
    k *= 1.f / fmaxf(sqrtf(nk), 1e-12f);
    kh[((size_t)h * JP + mm) * DH + lane] = (_Float16)k;
    vh[((size_t)h * JP + mm) * DH + lane] = (_Float16)v;
  } else if (gw < TP) {
    const int r = gw - TM;
    const int h = r / (JP - JTOT), jr = JTOT + r % (JP - JTOT);
    kh[((size_t)h * JP + jr) * DH + lane] = (_Float16)0.f;
    vh[((size_t)h * JP + jr) * DH + lane] = (_Float16)0.f;
  }
}

// ---------------------------------------------------------------------------
// vh[h][j][d] -> vT[h][d][j]
// ---------------------------------------------------------------------------
__global__ __launch_bounds__(256) void transpose_v(
    const _Float16* __restrict__ vh, _Float16* __restrict__ vT)
{
  __shared__ _Float16 tile[64][72];
  const int h = blockIdx.y;
  const int j0 = blockIdx.x * 64;
  const int t = threadIdx.x;
#pragma unroll
  for (int p = 0; p < 2; ++p) {
    const int jr = (t >> 3) + 32 * p;
    const int dc = (t & 7) * 8;
    half8 v = *(const half8*)(vh + ((size_t)h * JP + j0 + jr) * DH + dc);
    *(half8*)&tile[jr][dc] = v;
  }
  __syncthreads();
#pragma unroll
  for (int p = 0; p < 2; ++p) {
    const int d = (t >> 3) + 32 * p;
    const int jc = (t & 7) * 8;
    half8 o;
#pragma unroll
    for (int r = 0; r < 8; ++r) o[r] = tile[jc + r][d];
    *(half8*)(vT + ((size_t)h * DH + d) * JP + j0 + jc) = o;
  }
}

__device__ __forceinline__ int rel_bucket(int n) {
  if (n < 0) n = 0;
  if (n < 16) return n;
  int v = 16 + (int)(logf((float)n * 0.0625f) * 7.6944042f);
  return v > 31 ? 31 : v;
}

// ---------------------------------------------------------------------------
// Pass 1: MFMA QK^T -> pre-mix (k-chunked, low reg) -> running (m,l).
// ---------------------------------------------------------------------------
__global__ __launch_bounds__(256, 2) void attn_pass1(
    const _Float16* __restrict__ qh, const _Float16* __restrict__ kh,
    const float* __restrict__ pre_proj, const float* __restrict__ rel_table,
    float* __restrict__ mpart, float* __restrict__ lpart)
{
  const int i0 = blockIdx.x * 16;
  const int c = blockIdx.y;
  const int jlo = c * JSP;
  if (jlo >= i0 + 32) return;
  const int jhi = min((c < 3) ? jlo + JSP : JP, (i0 + 63) & ~31);
  const int tid = threadIdx.x;
  const int lane = tid & 63, w = tid >> 6;

  __shared__ float S_lds[32 * JPLANE];
  __shared__ float pre_s[256];
  __shared__ float relt[NB * NH];

  pre_s[tid] = pre_proj[tid];
  relt[tid] = rel_table[tid];
  relt[256 + tid] = rel_table[256 + tid];

  half8 qf[4][2];
#pragma unroll
  for (int n = 0; n < 4; ++n) {
    const int h = w * 4 + n;
    const _Float16* qb = qh + ((size_t)h * N_SEQ + i0 + (lane & 15)) * DH + (lane >> 4) * 8;
    qf[n][0] = *(const half8*)qb;
    qf[n][1] = *(const half8*)(qb + 32);
  }
  float m[16], l[16];
#pragma unroll
  for (int k = 0; k < 16; ++k) { m[k] = -1e30f; l[k] = 0.f; }
  const int mi = tid & 15;
  const int mj = tid >> 4;
  const int ig = i0 + mi;
  __syncthreads();

  for (int jb = jlo; jb < jhi; jb += 32) {
#pragma unroll
    for (int n = 0; n < 4; ++n) {
      const int h = w * 4 + n;
#pragma unroll
      for (int T = 0; T < 2; ++T) {
        floatx4 acc = {0.f, 0.f, 0.f, 0.f};
        const _Float16* kb = kh + ((size_t)h * JP + jb + 16 * T + (lane & 15)) * DH + (lane >> 4) * 8;
        acc = __builtin_amdgcn_mfma_f32_16x16x32_f16(qf[n][0], *(const half8*)kb, acc, 0, 0, 0);
        acc = __builtin_amdgcn_mfma_f32_16x16x32_f16(qf[n][1], *(const half8*)(kb + 32), acc, 0, 0, 0);
        const int jcol = (lane & 15) + 16 * T;
        const int row0 = (lane >> 4) * 4;
#pragma unroll
        for (int r = 0; r < 4; ++r) S_lds[jcol * JPLANE + h * 16 + row0 + r] = acc[r];
      }
    }
    __syncthreads();
    const int jg0 = jb + mj, jg1 = jg0 + 16;
    const bool v0 = (jg0 <= ig + MEM) && (jg0 < JTOT);
    const bool v1 = (jg1 <= ig + MEM) && (jg1 < JTOT);
    const int rb0 = rel_bucket(ig - jg0) * 16;
    const int rb1 = rel_bucket(ig - jg1) * 16;
#pragma unroll
    for (int kc = 0; kc < 2; ++kc) {
      float2 sa[8];
#pragma unroll
      for (int q = 0; q < 8; ++q) { sa[q].x = 0.f; sa[q].y = 0.f; }
#pragma unroll
      for (int h = 0; h < 16; ++h) {
        float s0 = S_lds[mj * JPLANE + h * 16 + mi];
        float s1 = S_lds[(mj + 16) * JPLANE + h * 16 + mi];
        float4 pa = *(const float4*)&pre_s[h * 16 + kc * 8];
        float4 pb = *(const float4*)&pre_s[h * 16 + kc * 8 + 4];
        sa[0].x += s0 * pa.x; sa[0].y += s1 * pa.x;
        sa[1].x += s0 * pa.y; sa[1].y += s1 * pa.y;
        sa[2].x += s0 * pa.z; sa[2].y += s1 * pa.z;
        sa[3].x += s0 * pa.w; sa[3].y += s1 * pa.w;
        sa[4].x += s0 * pb.x; sa[4].y += s1 * pb.x;
        sa[5].x += s0 * pb.y; sa[5].y += s1 * pb.y;
        sa[6].x += s0 * pb.z; sa[6].y += s1 * pb.z;
        sa[7].x += s0 * pb.w; sa[7].y += s1 * pb.w;
      }
#pragma unroll
      for (int kk = 0; kk < 8; ++kk) {
        const int k = kc * 8 + kk;
        float s0 = v0 ? sa[kk].x + relt[rb0 + k] * REL_SCALE : -1e30f;
        float s1 = v1 ? sa[kk].y + relt[rb1 + k] * REL_SCALE : -1e30f;
        float mn = fmaxf(m[k], fmaxf(s0, s1));
        float e0 = v0 ? __expf(s0 - mn) : 0.f;
        float e1 = v1 ? __expf(s1 - mn) : 0.f;
        l[k] = l[k] * __expf(m[k] - mn) + e0 + e1;
        m[k] = mn;
      }
    }
    __syncthreads();
  }
#pragma unroll
  for (int k = 0; k < 16; ++k) {
    S_lds[mj * JPLANE + k * 16 + mi] = m[k];
    S_lds[(16 + mj) * JPLANE + k * 16 + mi] = l[k];
  }
  __syncthreads();
  const int k = tid >> 4, i2 = tid & 15;
  float M = -1e30f;
#pragma unroll
  for (int jj = 0; jj < 16; ++jj) M = fmaxf(M, S_lds[jj * JPLANE + k * 16 + i2]);
  float L = 0.f;
#pragma unroll
  for (int jj = 0; jj < 16; ++jj)
    L += S_lds[(16 + jj) * JPLANE + k * 16 + i2] * __expf(S_lds[jj * JPLANE + k * 16 + i2] - M);
  mpart[((size_t)c * NH + k) * N_SEQ + i0 + i2] = M;
  lpart[((size_t)c * NH + k) * N_SEQ + i0 + i2] = L;
}

// ---------------------------------------------------------------------------
__global__ __launch_bounds__(256) void merge_ml(
    const float* __restrict__ mpart, const float* __restrict__ lpart,
    float* __restrict__ Mf, float* __restrict__ Lf)
{
  const int t = blockIdx.x * 256 + threadIdx.x;
  const int i = t & (N_SEQ - 1);
  const int lim = (i & ~15) + 32;
  const int h = t >> 11;
  float m = -1e30f;
#pragma unroll
  for (int c = 0; c < 4; ++c)
    if (c * JSP < lim) m = fmaxf(m, mpart[((size_t)c * NH + h) * N_SEQ + i]);
  float l = 0.f;
#pragma unroll
  for (int c = 0; c < 4; ++c)
    if (c * JSP < lim) {
      float mc = mpart[((size_t)c * NH + h) * N_SEQ + i];
      l += lpart[((size_t)c * NH + h) * N_SEQ + i] * __expf(mc - m);
    }
  Mf[t] = m;
  Lf[t] = l;
}

// ---------------------------------------------------------------------------
// Pass 2: MFMA QK^T -> pre-mix -> P -> fused post-mix -> MFMA PV.
// Low-register version: k-chunked premix, fused post accumulate, M/L in LDS.
// ---------------------------------------------------------------------------
__global__ __launch_bounds__(256, 2) void attn_pass2(
    const _Float16* __restrict__ qh, const _Float16* __restrict__ kh,
    const _Float16* __restrict__ vT,
    const float* __restrict__ pre_proj, const float* __restrict__ post_proj,
    const float* __restrict__ rel_table,
    const float* __restrict__ Mf, const float* __restrict__ Lf,
    float* __restrict__ opart)
{
  const int i0 = blockIdx.x * 16;
  const int c = blockIdx.y;
  const int jlo = c * JSP;
  if (jlo >= i0 + 32) return;
  const int jhi = min((c < 3) ? jlo + JSP : JP, (i0 + 63) & ~31);
  const int tid = threadIdx.x;
  const int lane = tid & 63, w = tid >> 6;

  __shared__ float S_lds[32 * JPLANE];          // 32,896 B
  __shared__ _Float16 P_lds[16 * 16 * 40];      // 20,480 B
  __shared__ float pre_s[256], post_s[256];
  __shared__ float relt[NB * NH];
  __shared__ float Ml[256], iLl[256];

  pre_s[tid] = pre_proj[tid];
  post_s[tid] = post_proj[tid];
  relt[tid] = rel_table[tid];
  relt[256 + tid] = rel_table[256 + tid];
  {
    const int k = tid >> 4, i2 = tid & 15;
    Ml[tid] = Mf[(size_t)k * N_SEQ + i0 + i2];
    iLl[tid] = 1.0f / Lf[(size_t)k * N_SEQ + i0 + i2];
  }

  const int mi = tid & 15;
  const int mj = tid >> 4;
  const int ig = i0 + mi;
  floatx4 oacc[4][4];
#pragma unroll
  for (int n = 0; n < 4; ++n)
#pragma unroll
    for (int T = 0; T < 4; ++T) oacc[n][T] = (floatx4){0.f, 0.f, 0.f, 0.f};
  __syncthreads();

  for (int jb = jlo; jb < jhi; jb += 32) {
    // ---- QK MFMA (q reloaded per block: L1-resident, saves 32 VGPRs) ----
#pragma unroll
    for (int n = 0; n < 4; ++n) {
      const int h = w * 4 + n;
      const _Float16* qb = qh + ((size_t)h * N_SEQ + i0 + (lane & 15)) * DH + (lane >> 4) * 8;
      half8 q0 = *(const half8*)qb;
      half8 q1 = *(const half8*)(qb + 32);
#pragma unroll
      for (int T = 0; T < 2; ++T) {
        floatx4 acc = {0.f, 0.f, 0.f, 0.f};
        const _Float16* kb = kh + ((size_t)h * JP + jb + 16 * T + (lane & 15)) * DH + (lane >> 4) * 8;
        acc = __builtin_amdgcn_mfma_f32_16x16x32_f16(q0, *(const half8*)kb, acc, 0, 0, 0);
        acc = __builtin_amdgcn_mfma_f32_16x16x32_f16(q1, *(const half8*)(kb + 32), acc, 0, 0, 0);
        const int jcol = (lane & 15) + 16 * T;
        const int row0 = (lane >> 4) * 4;
#pragma unroll
        for (int r = 0; r < 4; ++r) S_lds[jcol * JPLANE + h * 16 + row0 + r] = acc[r];
      }
    }
    __syncthreads();
    // ---- mixing: premix (k-chunks of 8) -> p -> fused post accumulate ----
    const int jg0 = jb + mj, jg1 = jg0 + 16;
    const bool v0 = (jg0 <= ig + MEM) && (jg0 < JTOT);
    const bool v1 = (jg1 <= ig + MEM) && (jg1 < JTOT);
    const int rb0 = rel_bucket(ig - jg0) * 16;
    const int rb1 = rel_bucket(ig - jg1) * 16;
    float2 o2[16];
#pragma unroll
    for (int q = 0; q < 16; ++q) { o2[q].x = 0.f; o2[q].y = 0.f; }
#pragma unroll
    for (int kc = 0; kc < 2; ++kc) {
      float2 sa[8];
#pragma unroll
      for (int q = 0; q < 8; ++q) { sa[q].x = 0.f; sa[q].y = 0.f; }
#pragma unroll
      for (int h = 0; h < 16; ++h) {
        float s0 = S_lds[mj * JPLANE + h * 16 + mi];
        float s1 = S_lds[(mj + 16) * JPLANE + h * 16 + mi];
        float4 pa = *(const float4*)&pre_s[h * 16 + kc * 8];
        float4 pb = *(const float4*)&pre_s[h * 16 + kc * 8 + 4];
        sa[0].x += s0 * pa.x; sa[0].y += s1 * pa.x;
        sa[1].x += s0 * pa.y; sa[1].y += s1 * pa.y;
        sa[2].x += s0 * pa.z; sa[2].y += s1 * pa.z;
        sa[3].x += s0 * pa.w; sa[3].y += s1 * pa.w;
        sa[4].x += s0 * pb.x; sa[4].y += s1 * pb.x;
        sa[5].x += s0 * pb.y; sa[5].y += s1 * pb.y;
        sa[6].x += s0 * pb.z; sa[6].y += s1 * pb.z;
        sa[7].x += s0 * pb.w; sa[7].y += s1 * pb.w;
      }
#pragma unroll
      for (int kk = 0; kk < 8; ++kk) {
        const int k = kc * 8 + kk;
        const float M = Ml[k * 16 + mi];
        const float il = iLl[k * 16 + mi];
        float p0 = v0 ? __expf(sa[kk].x + relt[rb0 + k] * REL_SCALE - M) * il : 0.f;
        float p1 = v1 ? __expf(sa[kk].y + relt[rb1 + k] * REL_SCALE - M) * il : 0.f;
#pragma unroll
        for (int kq = 0; kq < 4; ++kq) {
          float4 po = *(const float4*)&post_s[k * 16 + kq * 4];
          o2[kq * 4 + 0].x += p0 * po.x; o2[kq * 4 + 0].y += p1 * po.x;
          o2[kq * 4 + 1].x += p0 * po.y; o2[kq * 4 + 1].y += p1 * po.y;
          o2[kq * 4 + 2].x += p0 * po.z; o2[kq * 4 + 2].y += p1 * po.z;
          o2[kq * 4 + 3].x += p0 * po.w; o2[kq * 4 + 3].y += p1 * po.w;
        }
      }
    }
#pragma unroll
    for (int k2 = 0; k2 < 16; ++k2) {
      P_lds[(k2 * 16 + mi) * 40 + mj] = (_Float16)o2[k2].x;
      P_lds[(k2 * 16 + mi) * 40 + mj + 16] = (_Float16)o2[k2].y;
    }
    __syncthreads();
    // ---- PV MFMA ----
#pragma unroll
    for (int n = 0; n < 4; ++n) {
      const int h = w * 4 + n;
      half8 af = *(const half8*)&P_lds[((h * 16) + (lane & 15)) * 40 + (lane >> 4) * 8];
#pragma unroll
      for (int T = 0; T < 4; ++T) {
        const _Float16* vb = vT + ((size_t)h * DH + 16 * T + (lane & 15)) * JP + jb + (lane >> 4) * 8;
        oacc[n][T] = __builtin_amdgcn_mfma_f32_16x16x32_f16(af, *(const half8*)vb, oacc[n][T], 0, 0, 0);
      }
    }
    __syncthreads();
  }
#pragma unroll
  for (int n = 0; n < 4; ++n) {
    const int h = w * 4 + n;
#pragma unroll
    for (int T = 0; T < 4; ++T)
#pragma unroll
      for (int r = 0; r < 4; ++r) {
        const int row = (lane >> 4) * 4 + r;
        const int col = 16 * T + (lane & 15);
        opart[((size_t)c * N_SEQ + i0 + row) * DIMN + h * DH + col] = oacc[n][T][r];
      }
  }
}

// ---------------------------------------------------------------------------
// Merge O partials -> ctxh (fp16, A-layout for the final GEMM)
// ---------------------------------------------------------------------------
__global__ __launch_bounds__(256) void merge_ctx(
    const float* __restrict__ opart, _Float16* __restrict__ ctxh)
{
  const int t = blockIdx.x * 256 + threadIdx.x;
  const int i = t >> 8;
  const int c4 = t & 255;
  const int lim = (i & ~15) + 32;
  float4 acc = make_float4(0.f, 0.f, 0.f, 0.f);
#pragma unroll
  for (int c = 0; c < 4; ++c) {
    if (c * JSP < lim) {
      float4 v = ((const float4*)opart)[((size_t)c * N_SEQ + i) * 256 + c4];
      acc.x += v.x; acc.y += v.y; acc.z += v.z; acc.w += v.w;
    }
  }
  half4 o = { (_Float16)acc.x, (_Float16)acc.y, (_Float16)acc.z, (_Float16)acc.w };
  *(half4*)&ctxh[(size_t)i * DIMN + c4 * 4] = o;
}

// ---------------------------------------------------------------------------
extern "C" void kernel_launch(void* const* d_in, const int* in_sizes, int n_in,
                              void* d_out, int out_size, void* d_ws, size_t ws_size,
                              hipStream_t stream)
{
  const float* x         = (const float*)d_in[0];
  const float* rot       = (const float*)d_in[1];
  const float* Wq        = (const float*)d_in[2];
  const float* Wk        = (const float*)d_in[3];
  const float* Wv        = (const float*)d_in[4];
  const float* Wo        = (const float*)d_in[5];
  const float* bo        = (const float*)d_in[6];
  const float* mem_k     = (const float*)d_in[7];
  const float* mem_v     = (const float*)d_in[8];
  const float* pre_proj  = (const float*)d_in[9];
  const float* post_proj = (const float*)d_in[10];
  const float* qk_scale  = (const float*)d_in[11];
  const float* rel_table = (const float*)d_in[12];
  float* out = (float*)d_out;
  float* ws  = (float*)d_ws;

  // ---- workspace layout ----
  // floats: region (tmp 3*N*DIM early | opart 4*N*DIM late) + ml buffers
  float* region = ws;                              // 8,388,608 f
  float* tmp    = region;
  float* opart  = region;
  float* mpart  = region + 8388608;                // 131,072
  float* lpart  = mpart + 131072;                  // 131,072
  float* Mf     = lpart + 131072;                  // 32,768
  float* Lf     = Mf + 32768;                      // 32,768
  _Float16* xh  = (_Float16*)(Lf + 32768);         // 2,097,152 h
  _Float16* WqT = xh + 2097152;                    // 1,048,576 h
  _Float16* WkT = WqT + 1048576;
  _Float16* WvT = WkT + 1048576;
  _Float16* WoT = WvT + 1048576;
  _Float16* qh  = WoT + 1048576;                   // 2,097,152 h
  _Float16* kh  = qh + 2097152;                    // 2,162,688 h
  _Float16* vT  = kh + 2162688;                    // 2,162,688 h
  _Float16* vh  = xh;    // alias: xh(+start of WqT) dead after QKV GEMMs
  _Float16* ctxh = kh;   // alias: kh dead after attn_pass2
  (void)in_sizes; (void)n_in; (void)out_size; (void)ws_size;

  // ---- fp16 conversions ----
  convert_f16<<<2048, 256, 0, stream>>>(x, xh, N_SEQ * DIMN / 4);
  convtrans<<<dim3(16, 16), 256, 0, stream>>>(Wq, WqT, DIMN, DIMN);
  convtrans<<<dim3(16, 16), 256, 0, stream>>>(Wk, WkT, DIMN, DIMN);
  convtrans<<<dim3(16, 16), 256, 0, stream>>>(Wv, WvT, DIMN, DIMN);
  convtrans<<<dim3(16, 16), 256, 0, stream>>>(Wo, WoT, DIMN, DIMN);

  // ---- QKV projections (fp16 MFMA) ----
  dim3 gB(DIMN / 64, N_SEQ / 64);
  gemm_f16<<<gB, 256, 0, stream>>>(xh, WqT, tmp, nullptr, N_SEQ, DIMN, DIMN);
  gemm_f16<<<gB, 256, 0, stream>>>(xh, WkT, tmp + (size_t)N_SEQ * DIMN, nullptr, N_SEQ, DIMN, DIMN);
  gemm_f16<<<gB, 256, 0, stream>>>(xh, WvT, tmp + 2 * (size_t)N_SEQ * DIMN, nullptr, N_SEQ, DIMN, DIMN);

  {
    const int waves = NH * N_SEQ + NH * MEM + NH * (JP - JTOT);
    postproc<<<waves / 4, 256, 0, stream>>>(tmp, rot, mem_k, mem_v, qk_scale, qh, kh, vh);
  }
  transpose_v<<<dim3(JP / 64, NH), 256, 0, stream>>>(vh, vT);

  attn_pass1<<<dim3(N_SEQ / 16, 4), 256, 0, stream>>>(
      qh, kh, pre_proj, rel_table, mpart, lpart);
  merge_ml<<<NH * N_SEQ / 256, 256, 0, stream>>>(mpart, lpart, Mf, Lf);
  attn_pass2<<<dim3(N_SEQ / 16, 4), 256, 0, stream>>>(
      qh, kh, vT, pre_proj, post_proj, rel_table, Mf, Lf, opart);
  merge_ctx<<<(N_SEQ * DIMN / 4) / 256, 256, 0, stream>>>(opart, ctxh);

  // ---- output projection ----
  gemm_f16<<<gB, 256, 0, stream>>>(ctxh, WoT, out, bo, N_SEQ, DIMN, DIMN);
}

// Round 4
// 647.949 us; speedup vs baseline: 3.2061x; 2.3875x over previous
//
#include <hip/hip_runtime.h>
#include <math.h>
#include <float.h>

// Problem constants
#define N_SEQ 2048
#define DIMN  1024
#define NH    16
#define DH    64
#define ROT   32
#define MEM   16
#define JTOT  (N_SEQ + MEM)   // 2064
#define JP    2112            // padded to x32 (pad keys zeroed, masked)
#define NB    32
#define REL_SCALE 8.0f
#define C_SPLIT 6
#define JSP   352             // 11 tiles of 32; 6*352 = 2112 = JP
#define JPLANE 257            // LDS plane stride for S

typedef __attribute__((ext_vector_type(8))) _Float16 half8;
typedef __attribute__((ext_vector_type(4))) _Float16 half4;
typedef __attribute__((ext_vector_type(4))) float floatx4;

// ---------------------------------------------------------------------------
// f32 -> f16 elementwise (vectorized)
// ---------------------------------------------------------------------------
__global__ __launch_bounds__(256) void convert_f16(
    const float* __restrict__ in, _Float16* __restrict__ out, int n4)
{
  const int t = blockIdx.x * 256 + threadIdx.x;
  if (t >= n4) return;
  float4 v = ((const float4*)in)[t];
  half4 o = { (_Float16)v.x, (_Float16)v.y, (_Float16)v.z, (_Float16)v.w };
  *(half4*)&out[(size_t)t * 4] = o;
}

// ---------------------------------------------------------------------------
// W [K][N] f32 -> WT [N][K] f16 (64x64 LDS tiles)
// ---------------------------------------------------------------------------
__global__ __launch_bounds__(256) void convtrans(
    const float* __restrict__ W, _Float16* __restrict__ WT, int K, int N)
{
  __shared__ _Float16 tile[64][72];
  const int k0 = blockIdx.y * 64, n0 = blockIdx.x * 64;
  const int t = threadIdx.x;
#pragma unroll
  for (int p = 0; p < 4; ++p) {
    const int r = (t >> 4) + 16 * p;
    const int c = (t & 15) * 4;
    float4 wv = *(const float4*)&W[(size_t)(k0 + r) * N + n0 + c];
    tile[r][c + 0] = (_Float16)wv.x;
    tile[r][c + 1] = (_Float16)wv.y;
    tile[r][c + 2] = (_Float16)wv.z;
    tile[r][c + 3] = (_Float16)wv.w;
  }
  __syncthreads();
#pragma unroll
  for (int p = 0; p < 2; ++p) {
    const int n = (t >> 3) + 32 * p;
    const int kc = (t & 7) * 8;
    half8 o;
#pragma unroll
    for (int j = 0; j < 8; ++j) o[j] = tile[kc + j][n];
    *(half8*)&WT[(size_t)(n0 + n) * K + k0 + kc] = o;
  }
}

// ---------------------------------------------------------------------------
// fp16 MFMA GEMM: C(f32) = A(f16,[M][K]) @ BT(f16,[N][K])^T (+bias)
// ---------------------------------------------------------------------------
__global__ __launch_bounds__(256) void gemm_f16(
    const _Float16* __restrict__ A, const _Float16* __restrict__ BT,
    float* __restrict__ C, const float* __restrict__ bias,
    int M, int K, int N)
{
  const int tid = threadIdx.x;
  const int w = tid >> 6, lane = tid & 63;
  const int m0 = blockIdx.y * 64 + w * 16;
  const int n0 = blockIdx.x * 64;
  const int lr = lane & 15, lk = (lane >> 4) * 8;
  const _Float16* Ap = A + (size_t)(m0 + lr) * K + lk;
  const _Float16* Bp = BT + (size_t)(n0 + lr) * K + lk;
  floatx4 acc[4];
#pragma unroll
  for (int T = 0; T < 4; ++T) acc[T] = (floatx4){0.f, 0.f, 0.f, 0.f};
#pragma unroll 2
  for (int k0 = 0; k0 < K; k0 += 32) {
    half8 af = *(const half8*)(Ap + k0);
#pragma unroll
    for (int T = 0; T < 4; ++T) {
      half8 bf = *(const half8*)(Bp + (size_t)T * 16 * K + k0);
      acc[T] = __builtin_amdgcn_mfma_f32_16x16x32_f16(af, bf, acc[T], 0, 0, 0);
    }
  }
#pragma unroll
  for (int T = 0; T < 4; ++T) {
    const int col = n0 + T * 16 + lr;
    const float bb = bias ? bias[col] : 0.f;
#pragma unroll
    for (int r = 0; r < 4; ++r) {
      const int row = m0 + (lane >> 4) * 4 + r;
      C[(size_t)row * N + col] = acc[T][r] + bb;
    }
  }
}

// ---------------------------------------------------------------------------
// Rotary + l2norm + fp16 layout. qh scaled by 1/clip(exp(qk_scale),0.01).
// ---------------------------------------------------------------------------
__global__ __launch_bounds__(256) void postproc(
    const float* __restrict__ tmp, const float* __restrict__ rot,
    const float* __restrict__ mem_k, const float* __restrict__ mem_v,
    const float* __restrict__ qk_scale,
    _Float16* __restrict__ qh, _Float16* __restrict__ kh, _Float16* __restrict__ vh)
{
  const int gw = (blockIdx.x * 256 + threadIdx.x) >> 6;
  const int lane = threadIdx.x & 63;
  const int TQ = NH * N_SEQ;
  const int TM = TQ + NH * MEM;
  const int TP = TM + NH * (JP - JTOT);
  if (gw < TQ) {
    const int h = gw >> 11;
    const int i = gw & (N_SEQ - 1);
    const size_t base = (size_t)i * DIMN + h * DH + lane;
    float q = tmp[base];
    float k = tmp[base + (size_t)N_SEQ * DIMN];
    float v = tmp[base + 2 * (size_t)N_SEQ * DIMN];
    float cf = 1.f, sf = 0.f;
    if (lane < ROT) { float f = rot[(size_t)i * ROT + lane]; cf = cosf(f); sf = sinf(f); }
    float qp = __shfl_xor(q, 16);
    float kp = __shfl_xor(k, 16);
    float vp = __shfl_xor(v, 16);
    if (lane < ROT) {
      float sgn = (lane < 16) ? -1.f : 1.f;
      q = q * cf + sgn * qp * sf;
      k = k * cf + sgn * kp * sf;
      v = v * cf + sgn * vp * sf;
    }
    float nq = q * q, nk = k * k;
#pragma unroll
    for (int off = 32; off; off >>= 1) { nq += __shfl_xor(nq, off); nk += __shfl_xor(nk, off); }
    q *= 1.f / fmaxf(sqrtf(nq), 1e-12f);
    k *= 1.f / fmaxf(sqrtf(nk), 1e-12f);
    float scl = 1.0f / fmaxf(__expf(qk_scale[h]), 0.01f);
    qh[((size_t)h * N_SEQ + i) * DH + lane] = (_Float16)(q * scl);
    kh[((size_t)h * JP + MEM + i) * DH + lane] = (_Float16)k;
    vh[((size_t)h * JP + MEM + i) * DH + lane] = (_Float16)v;
  } else if (gw < TM) {
    const int r = gw - TQ;
    const int h = r >> 4, mm = r & 15;
    float k = mem_k[((size_t)h * MEM + mm) * DH + lane];
    float v = mem_v[((size_t)h * MEM + mm) * DH + lane];
    float nk = k * k;
#pragma unroll
    for (int off = 32; off; off >>= 1) nk += __shfl_xor(nk, off);
    k *= 1.f / fmaxf(sqrtf(nk), 1e-12f);
    kh[((size_t)h * JP + mm) * DH + lane] = (_Float16)k;
    vh[((size_t)h * JP + mm) * DH + lane] = (_Float16)v;
  } else if (gw < TP) {
    const int r = gw - TM;
    const int h = r / (JP - JTOT), jr = JTOT + r % (JP - JTOT);
    kh[((size_t)h * JP + jr) * DH + lane] = (_Float16)0.f;
    vh[((size_t)h * JP + jr) * DH + lane] = (_Float16)0.f;
  }
}

// ---------------------------------------------------------------------------
// vh[h][j][d] -> vT[h][d][j]
// ---------------------------------------------------------------------------
__global__ __launch_bounds__(256) void transpose_v(
    const _Float16* __restrict__ vh, _Float16* __restrict__ vT)
{
  __shared__ _Float16 tile[64][72];
  const int h = blockIdx.y;
  const int j0 = blockIdx.x * 64;
  const int t = threadIdx.x;
#pragma unroll
  for (int p = 0; p < 2; ++p) {
    const int jr = (t >> 3) + 32 * p;
    const int dc = (t & 7) * 8;
    half8 v = *(const half8*)(vh + ((size_t)h * JP + j0 + jr) * DH + dc);
    *(half8*)&tile[jr][dc] = v;
  }
  __syncthreads();
#pragma unroll
  for (int p = 0; p < 2; ++p) {
    const int d = (t >> 3) + 32 * p;
    const int jc = (t & 7) * 8;
    half8 o;
#pragma unroll
    for (int r = 0; r < 8; ++r) o[r] = tile[jc + r][d];
    *(half8*)(vT + ((size_t)h * DH + d) * JP + j0 + jc) = o;
  }
}

__device__ __forceinline__ int rel_bucket(int n) {
  if (n < 0) n = 0;
  if (n < 16) return n;
  int v = 16 + (int)(logf((float)n * 0.0625f) * 7.6944042f);
  return v > 31 ? 31 : v;
}

// ---------------------------------------------------------------------------
// Pass 1: MFMA QK^T -> pre-mix (k-chunked) -> running (m,l) per split.
// ---------------------------------------------------------------------------
__global__ __launch_bounds__(256, 2) void attn_pass1(
    const _Float16* __restrict__ qh, const _Float16* __restrict__ kh,
    const float* __restrict__ pre_proj, const float* __restrict__ rel_table,
    float* __restrict__ mpart, float* __restrict__ lpart)
{
  const int i0 = blockIdx.x * 16;
  const int c = blockIdx.y;
  const int jlo = c * JSP;
  if (jlo >= i0 + 32) return;
  const int jhi = min(min(jlo + JSP, JP), (i0 + 63) & ~31);
  const int tid = threadIdx.x;
  const int lane = tid & 63, w = tid >> 6;

  __shared__ float S_lds[32 * JPLANE];
  __shared__ float pre_s[256];
  __shared__ float relt[NB * NH];

  pre_s[tid] = pre_proj[tid];
  relt[tid] = rel_table[tid] * REL_SCALE;
  relt[256 + tid] = rel_table[256 + tid] * REL_SCALE;

  half8 qf[4][2];
#pragma unroll
  for (int n = 0; n < 4; ++n) {
    const int h = w * 4 + n;
    const _Float16* qb = qh + ((size_t)h * N_SEQ + i0 + (lane & 15)) * DH + (lane >> 4) * 8;
    qf[n][0] = *(const half8*)qb;
    qf[n][1] = *(const half8*)(qb + 32);
  }
  float m[16], l[16];
#pragma unroll
  for (int k = 0; k < 16; ++k) { m[k] = -1e30f; l[k] = 0.f; }
  const int mi = tid & 15;
  const int mj = tid >> 4;
  const int ig = i0 + mi;
  __syncthreads();

  for (int jb = jlo; jb < jhi; jb += 32) {
#pragma unroll
    for (int n = 0; n < 4; ++n) {
      const int h = w * 4 + n;
#pragma unroll
      for (int T = 0; T < 2; ++T) {
        floatx4 acc = {0.f, 0.f, 0.f, 0.f};
        const _Float16* kb = kh + ((size_t)h * JP + jb + 16 * T + (lane & 15)) * DH + (lane >> 4) * 8;
        acc = __builtin_amdgcn_mfma_f32_16x16x32_f16(qf[n][0], *(const half8*)kb, acc, 0, 0, 0);
        acc = __builtin_amdgcn_mfma_f32_16x16x32_f16(qf[n][1], *(const half8*)(kb + 32), acc, 0, 0, 0);
        const int jcol = (lane & 15) + 16 * T;
        const int row0 = (lane >> 4) * 4;
#pragma unroll
        for (int r = 0; r < 4; ++r) S_lds[jcol * JPLANE + h * 16 + row0 + r] = acc[r];
      }
    }
    __syncthreads();
    const int jg0 = jb + mj, jg1 = jg0 + 16;
    const bool v0 = (jg0 <= ig + MEM) && (jg0 < JTOT);
    const bool v1 = (jg1 <= ig + MEM) && (jg1 < JTOT);
    const int rb0 = rel_bucket(ig - jg0) * 16;
    const int rb1 = rel_bucket(ig - jg1) * 16;
#pragma unroll
    for (int kc = 0; kc < 2; ++kc) {
      float2 sa[8];
#pragma unroll
      for (int q = 0; q < 8; ++q) { sa[q].x = 0.f; sa[q].y = 0.f; }
#pragma unroll
      for (int h = 0; h < 16; ++h) {
        float s0 = S_lds[mj * JPLANE + h * 16 + mi];
        float s1 = S_lds[(mj + 16) * JPLANE + h * 16 + mi];
        float4 pa = *(const float4*)&pre_s[h * 16 + kc * 8];
        float4 pb = *(const float4*)&pre_s[h * 16 + kc * 8 + 4];
        sa[0].x += s0 * pa.x; sa[0].y += s1 * pa.x;
        sa[1].x += s0 * pa.y; sa[1].y += s1 * pa.y;
        sa[2].x += s0 * pa.z; sa[2].y += s1 * pa.z;
        sa[3].x += s0 * pa.w; sa[3].y += s1 * pa.w;
        sa[4].x += s0 * pb.x; sa[4].y += s1 * pb.x;
        sa[5].x += s0 * pb.y; sa[5].y += s1 * pb.y;
        sa[6].x += s0 * pb.z; sa[6].y += s1 * pb.z;
        sa[7].x += s0 * pb.w; sa[7].y += s1 * pb.w;
      }
#pragma unroll
      for (int kk = 0; kk < 8; ++kk) {
        const int k = kc * 8 + kk;
        float s0 = v0 ? sa[kk].x + relt[rb0 + k] : -1e30f;
        float s1 = v1 ? sa[kk].y + relt[rb1 + k] : -1e30f;
        float mn = fmaxf(m[k], fmaxf(s0, s1));
        float e0 = v0 ? __expf(s0 - mn) : 0.f;
        float e1 = v1 ? __expf(s1 - mn) : 0.f;
        l[k] = l[k] * __expf(m[k] - mn) + e0 + e1;
        m[k] = mn;
      }
    }
    __syncthreads();
  }
#pragma unroll
  for (int k = 0; k < 16; ++k) {
    S_lds[mj * JPLANE + k * 16 + mi] = m[k];
    S_lds[(16 + mj) * JPLANE + k * 16 + mi] = l[k];
  }
  __syncthreads();
  const int k = tid >> 4, i2 = tid & 15;
  float M = -1e30f;
#pragma unroll
  for (int jj = 0; jj < 16; ++jj) M = fmaxf(M, S_lds[jj * JPLANE + k * 16 + i2]);
  float L = 0.f;
#pragma unroll
  for (int jj = 0; jj < 16; ++jj)
    L += S_lds[(16 + jj) * JPLANE + k * 16 + i2] * __expf(S_lds[jj * JPLANE + k * 16 + i2] - M);
  mpart[((size_t)c * NH + k) * N_SEQ + i0 + i2] = M;
  lpart[((size_t)c * NH + k) * N_SEQ + i0 + i2] = L;
}

// ---------------------------------------------------------------------------
__global__ __launch_bounds__(256) void merge_ml(
    const float* __restrict__ mpart, const float* __restrict__ lpart,
    float* __restrict__ Mf, float* __restrict__ Lf)
{
  const int t = blockIdx.x * 256 + threadIdx.x;
  const int i = t & (N_SEQ - 1);
  const int lim = (i & ~15) + 32;
  const int h = t >> 11;
  float m = -1e30f;
#pragma unroll
  for (int c = 0; c < C_SPLIT; ++c)
    if (c * JSP < lim) m = fmaxf(m, mpart[((size_t)c * NH + h) * N_SEQ + i]);
  float l = 0.f;
#pragma unroll
  for (int c = 0; c < C_SPLIT; ++c)
    if (c * JSP < lim) {
      float mc = mpart[((size_t)c * NH + h) * N_SEQ + i];
      l += lpart[((size_t)c * NH + h) * N_SEQ + i] * __expf(mc - m);
    }
  Mf[t] = m;
  Lf[t] = l;
}

// ---------------------------------------------------------------------------
// Pass 2: QK MFMA -> premix -> p staged in LDS (fp16, thread-private rows)
// -> low-register postmix -> P2 fp16 -> PV MFMA -> atomic O into ctx.
// ---------------------------------------------------------------------------
__global__ __launch_bounds__(256, 2) void attn_pass2(
    const _Float16* __restrict__ qh, const _Float16* __restrict__ kh,
    const _Float16* __restrict__ vT,
    const float* __restrict__ pre_proj, const float* __restrict__ post_proj,
    const float* __restrict__ rel_table,
    const float* __restrict__ Mf, const float* __restrict__ Lf,
    float* __restrict__ ctx)
{
  const int i0 = blockIdx.x * 16;
  const int c = blockIdx.y;
  const int jlo = c * JSP;
  if (jlo >= i0 + 32) return;
  const int jhi = min(min(jlo + JSP, JP), (i0 + 63) & ~31);
  const int tid = threadIdx.x;
  const int lane = tid & 63, w = tid >> 6;

  __shared__ float S_lds[32 * JPLANE];      // 32,896 B
  __shared__ _Float16 Pp[512 * 20];         // 20,480 B  p staging (per-thread rows)
  __shared__ _Float16 P_lds[256 * 40];      // 20,480 B  P2 for PV A-frags
  __shared__ float pre_s[256], post_s[256];
  __shared__ float relt[NB * NH];
  __shared__ float Ml[256], iLl[256];

  pre_s[tid] = pre_proj[tid];
  post_s[tid] = post_proj[tid];
  relt[tid] = rel_table[tid] * REL_SCALE;
  relt[256 + tid] = rel_table[256 + tid] * REL_SCALE;
  {
    const int k = tid >> 4, i2 = tid & 15;
    Ml[tid] = Mf[(size_t)k * N_SEQ + i0 + i2];
    iLl[tid] = 1.0f / Lf[(size_t)k * N_SEQ + i0 + i2];
  }

  const int mi = tid & 15;
  const int mj = tid >> 4;
  const int ig = i0 + mi;
  const int pair0 = mj * 16 + mi;        // rows of Pp owned by this thread
  const int pair1 = (mj + 16) * 16 + mi;
  floatx4 oacc[4][4];
#pragma unroll
  for (int n = 0; n < 4; ++n)
#pragma unroll
    for (int T = 0; T < 4; ++T) oacc[n][T] = (floatx4){0.f, 0.f, 0.f, 0.f};
  __syncthreads();

  for (int jb = jlo; jb < jhi; jb += 32) {
    // ---- QK MFMA -> S_lds ----
#pragma unroll
    for (int n = 0; n < 4; ++n) {
      const int h = w * 4 + n;
      const _Float16* qb = qh + ((size_t)h * N_SEQ + i0 + (lane & 15)) * DH + (lane >> 4) * 8;
      half8 q0 = *(const half8*)qb;
      half8 q1 = *(const half8*)(qb + 32);
#pragma unroll
      for (int T = 0; T < 2; ++T) {
        floatx4 acc = {0.f, 0.f, 0.f, 0.f};
        const _Float16* kb = kh + ((size_t)h * JP + jb + 16 * T + (lane & 15)) * DH + (lane >> 4) * 8;
        acc = __builtin_amdgcn_mfma_f32_16x16x32_f16(q0, *(const half8*)kb, acc, 0, 0, 0);
        acc = __builtin_amdgcn_mfma_f32_16x16x32_f16(q1, *(const half8*)(kb + 32), acc, 0, 0, 0);
        const int jcol = (lane & 15) + 16 * T;
        const int row0 = (lane >> 4) * 4;
#pragma unroll
        for (int r = 0; r < 4; ++r) S_lds[jcol * JPLANE + h * 16 + row0 + r] = acc[r];
      }
    }
    __syncthreads();
    // ---- premix + softmax-normalize -> Pp (own rows, no barrier needed) ----
    const int jg0 = jb + mj, jg1 = jg0 + 16;
    const bool v0 = (jg0 <= ig + MEM) && (jg0 < JTOT);
    const bool v1 = (jg1 <= ig + MEM) && (jg1 < JTOT);
    const int rb0 = rel_bucket(ig - jg0) * 16;
    const int rb1 = rel_bucket(ig - jg1) * 16;
#pragma unroll
    for (int kc = 0; kc < 2; ++kc) {
      float2 sa[8];
#pragma unroll
      for (int q = 0; q < 8; ++q) { sa[q].x = 0.f; sa[q].y = 0.f; }
#pragma unroll
      for (int h = 0; h < 16; ++h) {
        float s0 = S_lds[mj * JPLANE + h * 16 + mi];
        float s1 = S_lds[(mj + 16) * JPLANE + h * 16 + mi];
        float4 pa = *(const float4*)&pre_s[h * 16 + kc * 8];
        float4 pb = *(const float4*)&pre_s[h * 16 + kc * 8 + 4];
        sa[0].x += s0 * pa.x; sa[0].y += s1 * pa.x;
        sa[1].x += s0 * pa.y; sa[1].y += s1 * pa.y;
        sa[2].x += s0 * pa.z; sa[2].y += s1 * pa.z;
        sa[3].x += s0 * pa.w; sa[3].y += s1 * pa.w;
        sa[4].x += s0 * pb.x; sa[4].y += s1 * pb.x;
        sa[5].x += s0 * pb.y; sa[5].y += s1 * pb.y;
        sa[6].x += s0 * pb.z; sa[6].y += s1 * pb.z;
        sa[7].x += s0 * pb.w; sa[7].y += s1 * pb.w;
      }
      half4 w0a, w0b, w1a, w1b;
#pragma unroll
      for (int kk = 0; kk < 8; ++kk) {
        const int k = kc * 8 + kk;
        const float M = Ml[k * 16 + mi];
        const float il = iLl[k * 16 + mi];
        float p0 = v0 ? __expf(sa[kk].x + relt[rb0 + k] - M) * il : 0.f;
        float p1 = v1 ? __expf(sa[kk].y + relt[rb1 + k] - M) * il : 0.f;
        if (kk < 4) { w0a[kk] = (_Float16)p0; w1a[kk] = (_Float16)p1; }
        else        { w0b[kk - 4] = (_Float16)p0; w1b[kk - 4] = (_Float16)p1; }
      }
      *(half4*)&Pp[pair0 * 20 + kc * 8]     = w0a;
      *(half4*)&Pp[pair0 * 20 + kc * 8 + 4] = w0b;
      *(half4*)&Pp[pair1 * 20 + kc * 8]     = w1a;
      *(half4*)&Pp[pair1 * 20 + kc * 8 + 4] = w1b;
    }
    // ---- postmix in two output-halves (reads own Pp rows) -> P_lds ----
#pragma unroll
    for (int H = 0; H < 2; ++H) {
      float2 o2[8];
#pragma unroll
      for (int q = 0; q < 8; ++q) { o2[q].x = 0.f; o2[q].y = 0.f; }
#pragma unroll
      for (int kc4 = 0; kc4 < 4; ++kc4) {
        half4 pa = *(const half4*)&Pp[pair0 * 20 + kc4 * 4];
        half4 pb = *(const half4*)&Pp[pair1 * 20 + kc4 * 4];
#pragma unroll
        for (int r = 0; r < 4; ++r) {
          const int k = kc4 * 4 + r;
          const float p0 = (float)pa[r], p1 = (float)pb[r];
          float4 q0 = *(const float4*)&post_s[k * 16 + H * 8];
          float4 q1 = *(const float4*)&post_s[k * 16 + H * 8 + 4];
          o2[0].x += p0 * q0.x; o2[0].y += p1 * q0.x;
          o2[1].x += p0 * q0.y; o2[1].y += p1 * q0.y;
          o2[2].x += p0 * q0.z; o2[2].y += p1 * q0.z;
          o2[3].x += p0 * q0.w; o2[3].y += p1 * q0.w;
          o2[4].x += p0 * q1.x; o2[4].y += p1 * q1.x;
          o2[5].x += p0 * q1.y; o2[5].y += p1 * q1.y;
          o2[6].x += p0 * q1.z; o2[6].y += p1 * q1.z;
          o2[7].x += p0 * q1.w; o2[7].y += p1 * q1.w;
        }
      }
#pragma unroll
      for (int kq = 0; kq < 8; ++kq) {
        P_lds[((H * 8 + kq) * 16 + mi) * 40 + mj]      = (_Float16)o2[kq].x;
        P_lds[((H * 8 + kq) * 16 + mi) * 40 + mj + 16] = (_Float16)o2[kq].y;
      }
    }
    __syncthreads();
    // ---- PV MFMA ----
#pragma unroll
    for (int n = 0; n < 4; ++n) {
      const int h = w * 4 + n;
      half8 af = *(const half8*)&P_lds[((h * 16) + (lane & 15)) * 40 + (lane >> 4) * 8];
#pragma unroll
      for (int T = 0; T < 4; ++T) {
        const _Float16* vb = vT + ((size_t)h * DH + 16 * T + (lane & 15)) * JP + jb + (lane >> 4) * 8;
        oacc[n][T] = __builtin_amdgcn_mfma_f32_16x16x32_f16(af, *(const half8*)vb, oacc[n][T], 0, 0, 0);
      }
    }
    __syncthreads();
  }
  // ---- atomic accumulate into ctx ----
#pragma unroll
  for (int n = 0; n < 4; ++n) {
    const int h = w * 4 + n;
#pragma unroll
    for (int T = 0; T < 4; ++T)
#pragma unroll
      for (int r = 0; r < 4; ++r) {
        const int row = i0 + (lane >> 4) * 4 + r;
        const int col = h * DH + 16 * T + (lane & 15);
        atomicAdd(&ctx[(size_t)row * DIMN + col], oacc[n][T][r]);
      }
  }
}

// ---------------------------------------------------------------------------
extern "C" void kernel_launch(void* const* d_in, const int* in_sizes, int n_in,
                              void* d_out, int out_size, void* d_ws, size_t ws_size,
                              hipStream_t stream)
{
  const float* x         = (const float*)d_in[0];
  const float* rot       = (const float*)d_in[1];
  const float* Wq        = (const float*)d_in[2];
  const float* Wk        = (const float*)d_in[3];
  const float* Wv        = (const float*)d_in[4];
  const float* Wo        = (const float*)d_in[5];
  const float* bo        = (const float*)d_in[6];
  const float* mem_k     = (const float*)d_in[7];
  const float* mem_v     = (const float*)d_in[8];
  const float* pre_proj  = (const float*)d_in[9];
  const float* post_proj = (const float*)d_in[10];
  const float* qk_scale  = (const float*)d_in[11];
  const float* rel_table = (const float*)d_in[12];
  float* out = (float*)d_out;
  float* ws  = (float*)d_ws;

  // ---- workspace layout (~57 MB) ----
  float* tmp    = ws;                              // 3*N*DIM = 6,291,456 f
  float* ctx    = ws;                              // aliases tmp (tmp dead first)
  float* mpart  = ws + 6291456;                    // 6*16*2048 = 196,608
  float* lpart  = mpart + 196608;
  float* Mf     = lpart + 196608;                  // 32,768
  float* Lf     = Mf + 32768;
  _Float16* xh  = (_Float16*)(Lf + 32768);         // 2,097,152 h
  _Float16* WqT = xh + 2097152;                    // 1,048,576 h each
  _Float16* WkT = WqT + 1048576;
  _Float16* WvT = WkT + 1048576;
  _Float16* WoT = WvT + 1048576;
  _Float16* qh  = WoT + 1048576;                   // 2,097,152 h
  _Float16* kh  = qh + 2097152;                    // 2,162,688 h
  _Float16* vT  = kh + 2162688;                    // 2,162,688 h
  _Float16* vh  = vT + 2162688;                    // 2,162,688 h
  _Float16* ctxh = xh;   // alias: xh dead after QKV GEMMs
  (void)in_sizes; (void)n_in; (void)out_size; (void)ws_size;

  // ---- fp16 conversions ----
  convert_f16<<<2048, 256, 0, stream>>>(x, xh, N_SEQ * DIMN / 4);
  convtrans<<<dim3(16, 16), 256, 0, stream>>>(Wq, WqT, DIMN, DIMN);
  convtrans<<<dim3(16, 16), 256, 0, stream>>>(Wk, WkT, DIMN, DIMN);
  convtrans<<<dim3(16, 16), 256, 0, stream>>>(Wv, WvT, DIMN, DIMN);
  convtrans<<<dim3(16, 16), 256, 0, stream>>>(Wo, WoT, DIMN, DIMN);

  // ---- QKV projections (fp16 MFMA) ----
  dim3 gB(DIMN / 64, N_SEQ / 64);
  gemm_f16<<<gB, 256, 0, stream>>>(xh, WqT, tmp, nullptr, N_SEQ, DIMN, DIMN);
  gemm_f16<<<gB, 256, 0, stream>>>(xh, WkT, tmp + (size_t)N_SEQ * DIMN, nullptr, N_SEQ, DIMN, DIMN);
  gemm_f16<<<gB, 256, 0, stream>>>(xh, WvT, tmp + 2 * (size_t)N_SEQ * DIMN, nullptr, N_SEQ, DIMN, DIMN);

  {
    const int waves = NH * N_SEQ + NH * MEM + NH * (JP - JTOT);
    postproc<<<waves / 4, 256, 0, stream>>>(tmp, rot, mem_k, mem_v, qk_scale, qh, kh, vh);
  }
  transpose_v<<<dim3(JP / 64, NH), 256, 0, stream>>>(vh, vT);

  // ctx zero-init (tmp is dead now); pass2 accumulates atomically
  hipMemsetAsync(ctx, 0, (size_t)N_SEQ * DIMN * sizeof(float), stream);

  attn_pass1<<<dim3(N_SEQ / 16, C_SPLIT), 256, 0, stream>>>(
      qh, kh, pre_proj, rel_table, mpart, lpart);
  merge_ml<<<NH * N_SEQ / 256, 256, 0, stream>>>(mpart, lpart, Mf, Lf);
  attn_pass2<<<dim3(N_SEQ / 16, C_SPLIT), 256, 0, stream>>>(
      qh, kh, vT, pre_proj, post_proj, rel_table, Mf, Lf, ctx);

  convert_f16<<<2048, 256, 0, stream>>>(ctx, ctxh, N_SEQ * DIMN / 4);
  gemm_f16<<<gB, 256, 0, stream>>>(ctxh, WoT, out, bo, N_SEQ, DIMN, DIMN);
}